// Round 6
// baseline (508.417 us; speedup 1.0000x reference)
//
#include <hip/hip_runtime.h>
#include <hip/hip_fp16.h>

namespace {
constexpr int B_   = 32;
constexpr int CIN  = 64;
constexpr int H    = 128;
constexpr int L    = 4096;
constexpr int TL   = 128;           // output positions per block
constexpr int HALO = 30;
constexpr int ROWS = 158;           // HALO + TL
constexpr int NT   = L / TL;        // 32
constexpr float EPS = 1e-5f;
}

typedef __attribute__((ext_vector_type(8))) _Float16 half8;   // 8 f16 (4 VGPRs)
typedef __attribute__((ext_vector_type(4))) float f32x4;

union FragU { unsigned u[4]; half8 h; };

// f16 h tile, position-major [row][128 ch], 256 B/row, 16B-chunk XOR swizzle:
// chunk' = chunk ^ (row & 15) -> 16 consecutive rows hit 16 distinct chunks.
__device__ __forceinline__ int HOFF(int row, int ch) {
    return (row << 8) + ((((ch >> 3) ^ (row & 15)) << 4) | ((ch & 7) << 1));
}
__device__ __forceinline__ float2 unpk(unsigned u) {          // (lo, hi) f16 -> f32
    union { unsigned u; __half2 h; } c; c.u = u;
    return __half22float2(c.h);
}
__device__ __forceinline__ float f16lo(unsigned short u) {
    __half_raw r; r.x = u;
    return __half2float(__half(r));
}
__device__ __forceinline__ unsigned pk(float a, float b) {    // lo=f16(a), hi=f16(b), RN
    union { __half2 h; unsigned u; } c;
    c.h = __floats2half2_rn(a, b);
    return c.u;
}

// ---- prep: weights f32 -> f16 in exact MFMA B-fragment layout; BN folded params ----
// frag element j of lane: n = ot*16 + (lane&15), k = kt*32 + (lane>>4)*4 + (j&3) + 16*(j>>2)
__global__ void prep(const float* __restrict__ pw_w0,
                     const float* __restrict__ pw_w_rest,
                     const float* __restrict__ res_w,
                     const float* __restrict__ pw_b,
                     const float* __restrict__ bn_g,
                     const float* __restrict__ bn_b,
                     const float* __restrict__ bn_m,
                     const float* __restrict__ bn_v,
                     unsigned short* __restrict__ Wsh,   // 65536 f16 (128 KiB)
                     float* __restrict__ prm)            // 1024 f32
{
    const int g = blockIdx.x * 512 + threadIdx.x;        // one f16 each
    {
        const int F = g >> 9;            // frag 0..127
        const int r = g & 511;
        const int lane = r >> 3, j = r & 7;
        const int blk = F >> 5;          // 0:L0(Y+R) 1..3:L1..L3
        const int f = F & 31;
        float v;
        if (blk == 0) {
            const int ff = f & 15;                        // Y: f=0..15, R: f=16..31
            const int kt = ff >> 3, ot = ff & 7;          // K=64 -> kt 0..1
            const int n = ot * 16 + (lane & 15);
            const int k = kt * 32 + ((lane >> 4) << 2) + (j & 3) + ((j >> 2) << 4);
            const float* src = (f >> 4) ? res_w : pw_w0;
            v = src[n * 64 + k];
        } else {
            const int kt = f >> 3, ot = f & 7;            // K=128 -> kt 0..3 (R5 BUGFIX)
            const int n = ot * 16 + (lane & 15);
            const int k = kt * 32 + ((lane >> 4) << 2) + (j & 3) + ((j >> 2) << 4);
            v = pw_w_rest[(size_t)(blk - 1) * H * H + n * H + k];
        }
        const __half hv = __float2half(v);
        Wsh[g] = __half_as_ushort(hv);
    }
    if (blockIdx.x == 0) {
        for (int idx = threadIdx.x; idx < 1024; idx += 512) {
            const int li = idx >> 8;
            const int rest = idx & 255;
            const int ch = rest & 127;
            const int isC = rest >> 7;
            const float A  = bn_g[li * H + ch] * rsqrtf(bn_v[li * H + ch] + EPS);
            const float Cc = fmaf(A, pw_b[li * H + ch] - bn_m[li * H + ch], bn_b[li * H + ch]);
            prm[li * 256 + isC * 128 + ch] = isC ? Cc : A;
        }
    }
}

__global__ __launch_bounds__(512, 4) void tcn_mfma(
    const float* __restrict__ x,
    const float* __restrict__ sc_w,
    const float* __restrict__ res_b,
    const float* __restrict__ out_w,
    const float* __restrict__ out_b,
    const unsigned short* __restrict__ Wsh,
    const float* __restrict__ prm,
    float* __restrict__ out)
{
    __shared__ __align__(16) char smem[160 * 256 + 32768];  // 72 KiB -> 2 blocks/CU
    char* hb = smem;                     // f16 h [160][128] swizzled
    char* Wl = smem + 160 * 256;         // 32 KiB staged B-fragments

    const int tile = blockIdx.x;
    const int b    = blockIdx.y;
    const int s    = tile * TL;
    const int tid  = threadIdx.x;
    const int lane = tid & 63;
    const int wave = tid >> 6;

    // ---- stage x -> f16, transposed+swizzled ----
    const float* xb = x + (size_t)b * CIN * L;
    for (int c = wave; c < CIN; c += 8) {
        for (int j = lane; j < ROWS; j += 64) {
            const int p = s - HALO + j;
            const float v = (p >= 0) ? xb[(size_t)c * L + p] : 0.0f;
            *(unsigned short*)(hb + HOFF(j, c)) = __half_as_ushort(__float2half(v));
        }
    }

    auto stageW = [&](int layerBlk) {     // 32 KiB global -> LDS
        const unsigned short* src = Wsh + layerBlk * 16384;
        #pragma unroll
        for (int it = 0; it < 4; ++it) {
            const int idx = it * 512 + tid;
            *(uint4*)(Wl + idx * 16) = *(const uint4*)(src + idx * 8);
        }
    };
    stageW(0);

    const float w00 = sc_w[0], w01 = sc_w[1], w02 = sc_w[2];

    auto tileWrite = [&](int pb, const unsigned* stash) {
        const int o0 = lane & 15;
        const int coff = (lane >> 4) << 2;
        #pragma unroll
        for (int ot = 0; ot < 8; ++ot) {
            const int o = ot * 16 + o0;
            const unsigned wa = stash[ot * 2], wb = stash[ot * 2 + 1];
            *(unsigned short*)(hb + HOFF(pb + coff + 0, o)) = (unsigned short)(wa & 0xffff);
            *(unsigned short*)(hb + HOFF(pb + coff + 1, o)) = (unsigned short)(wa >> 16);
            *(unsigned short*)(hb + HOFF(pb + coff + 2, o)) = (unsigned short)(wb & 0xffff);
            *(unsigned short*)(hb + HOFF(pb + coff + 3, o)) = (unsigned short)(wb >> 16);
        }
    };

    __syncthreads();   // x + W0 staged

    // =================== layer 0: Y-GEMM (K=64) + residual 1x1 GEMM ===================
    {
        auto l0_tile = [&](int pb, unsigned* stash) {
            f32x4 accY[8], accR[8];
            #pragma unroll
            for (int ot = 0; ot < 8; ++ot) { accY[ot] = f32x4{0,0,0,0}; accR[ot] = f32x4{0,0,0,0}; }
            const int row0 = pb + (lane & 15);
            const int coff = (lane >> 4) << 2;
            #pragma unroll
            for (int kt = 0; kt < 2; ++kt) {
                const int cb = kt * 32 + coff;
                const uint2 u0a = *(const uint2*)(hb + HOFF(row0,     cb));
                const uint2 u0b = *(const uint2*)(hb + HOFF(row0,     cb + 16));
                const uint2 u1a = *(const uint2*)(hb + HOFF(row0 - 1, cb));
                const uint2 u1b = *(const uint2*)(hb + HOFF(row0 - 1, cb + 16));
                const uint2 u2a = *(const uint2*)(hb + HOFF(row0 - 2, cb));
                const uint2 u2b = *(const uint2*)(hb + HOFF(row0 - 2, cb + 16));
                const unsigned q0[4] = {u0a.x, u0a.y, u0b.x, u0b.y};
                const unsigned q1[4] = {u1a.x, u1a.y, u1b.x, u1b.y};
                const unsigned q2[4] = {u2a.x, u2a.y, u2b.x, u2b.y};
                FragU aU, rU;
                #pragma unroll
                for (int q = 0; q < 4; ++q) {
                    const float2 t0 = unpk(q0[q]);
                    const float2 t1 = unpk(q1[q]);
                    const float2 t2 = unpk(q2[q]);
                    const float dl = fmaf(w02, t0.x, fmaf(w01, t1.x, w00 * t2.x));
                    const float dh = fmaf(w02, t0.y, fmaf(w01, t1.y, w00 * t2.y));
                    aU.u[q] = pk(dl, dh);
                    rU.u[q] = q0[q];                   // raw x taps = residual A-frag
                }
                #pragma unroll
                for (int ot = 0; ot < 8; ++ot) {
                    const half8 bY = *(const half8*)(Wl + (kt * 8 + ot) * 1024 + lane * 16);
                    accY[ot] = __builtin_amdgcn_mfma_f32_16x16x32_f16(aU.h, bY, accY[ot], 0, 0, 0);
                }
                #pragma unroll
                for (int ot = 0; ot < 8; ++ot) {
                    const half8 bR = *(const half8*)(Wl + (16 + kt * 8 + ot) * 1024 + lane * 16);
                    accR[ot] = __builtin_amdgcn_mfma_f32_16x16x32_f16(rU.h, bR, accR[ot], 0, 0, 0);
                }
            }
            #pragma unroll
            for (int ot = 0; ot < 8; ++ot) {
                const int o = ot * 16 + (lane & 15);
                const float A  = prm[o];
                const float Cc = prm[128 + o];
                const float rb = res_b[o];
                float v[4];
                #pragma unroll
                for (int r = 0; r < 4; ++r) {
                    const int row = pb + coff + r;
                    const float y = fmaxf(fmaf(A, accY[ot][r], Cc), 0.0f);
                    float vv = fmaxf(y + accR[ot][r] + rb, 0.0f);
                    if (s - HALO + row < 0) vv = 0.0f;   // causal zero-pad (tile 0)
                    v[r] = vv;
                }
                stash[ot * 2]     = pk(v[0], v[1]);
                stash[ot * 2 + 1] = pk(v[2], v[3]);
            }
        };
        unsigned st1[16], st2[16];
        const int pb1 = 2 + 16 * wave;                                     // 2..114
        const int pb2 = (wave < 2) ? min(2 + 16 * (8 + wave), ROWS - 16) : -1;  // 130,142
        l0_tile(pb1, st1);
        if (pb2 >= 0) l0_tile(pb2, st2);
        __syncthreads();                  // all reads of x done
        tileWrite(pb1, st1);
        if (pb2 >= 0) tileWrite(pb2, st2);
        __syncthreads();                  // h1 visible
    }

    // =================== layers 1..3 ===================
    #pragma unroll
    for (int li = 1; li < 4; ++li) {
        const int dil = 1 << li;
        const int jstart = (li == 1) ? 6 : (li == 2) ? 14 : 30;
        const float lw0 = sc_w[li * 3], lw1 = sc_w[li * 3 + 1], lw2 = sc_w[li * 3 + 2];

        stageW(li);                       // Wl reads of prev layer finished pre-barrier
        __syncthreads();

        auto gemm_tile = [&](int pb, unsigned* stash) {
            f32x4 acc[8];
            #pragma unroll
            for (int ot = 0; ot < 8; ++ot) acc[ot] = f32x4{0,0,0,0};
            const int row0 = pb + (lane & 15);
            const int coff = (lane >> 4) << 2;
            #pragma unroll
            for (int kt = 0; kt < 4; ++kt) {
                const int cb = kt * 32 + coff;
                const uint2 u0a = *(const uint2*)(hb + HOFF(row0,           cb));
                const uint2 u0b = *(const uint2*)(hb + HOFF(row0,           cb + 16));
                const uint2 u1a = *(const uint2*)(hb + HOFF(row0 - dil,     cb));
                const uint2 u1b = *(const uint2*)(hb + HOFF(row0 - dil,     cb + 16));
                const uint2 u2a = *(const uint2*)(hb + HOFF(row0 - 2 * dil, cb));
                const uint2 u2b = *(const uint2*)(hb + HOFF(row0 - 2 * dil, cb + 16));
                const unsigned q0[4] = {u0a.x, u0a.y, u0b.x, u0b.y};
                const unsigned q1[4] = {u1a.x, u1a.y, u1b.x, u1b.y};
                const unsigned q2[4] = {u2a.x, u2a.y, u2b.x, u2b.y};
                FragU aU;
                #pragma unroll
                for (int q = 0; q < 4; ++q) {
                    const float2 t0 = unpk(q0[q]);
                    const float2 t1 = unpk(q1[q]);
                    const float2 t2 = unpk(q2[q]);
                    const float dl = fmaf(lw2, t0.x, fmaf(lw1, t1.x, lw0 * t2.x));
                    const float dh = fmaf(lw2, t0.y, fmaf(lw1, t1.y, lw0 * t2.y));
                    aU.u[q] = pk(dl, dh);
                }
                #pragma unroll
                for (int ot = 0; ot < 8; ++ot) {
                    const half8 bb = *(const half8*)(Wl + (kt * 8 + ot) * 1024 + lane * 16);
                    acc[ot] = __builtin_amdgcn_mfma_f32_16x16x32_f16(aU.h, bb, acc[ot], 0, 0, 0);
                }
            }
            #pragma unroll
            for (int ot = 0; ot < 8; ++ot) {
                const int o = ot * 16 + (lane & 15);
                const float A  = prm[li * 256 + o];
                const float Cc = prm[li * 256 + 128 + o];
                float v[4];
                #pragma unroll
                for (int r = 0; r < 4; ++r) {
                    const int row = pb + coff + r;
                    const float y = fmaxf(fmaf(A, acc[ot][r], Cc), 0.0f);
                    const unsigned short rr = *(const unsigned short*)(hb + HOFF(row, o));
                    float vv = fmaxf(y + f16lo(rr), 0.0f);        // identity residual
                    if (s - HALO + row < 0) vv = 0.0f;            // causal zero-pad (tile 0)
                    v[r] = vv;
                }
                stash[ot * 2]     = pk(v[0], v[1]);
                stash[ot * 2 + 1] = pk(v[2], v[3]);
            }
        };

        int t2 = -1;
        if (li == 1 && (wave == 2 || wave == 3)) t2 = 6 + wave;   // tiles 8,9
        if (li == 2 && wave == 4) t2 = 8;
        const int pb1 = min(jstart + 16 * wave, ROWS - 16);
        const int pb2 = (t2 >= 0) ? min(jstart + 16 * t2, ROWS - 16) : -1;

        unsigned st1[16], st2[16];
        gemm_tile(pb1, st1);
        if (pb2 >= 0) gemm_tile(pb2, st2);
        __syncthreads();                  // all reads of h_li done
        tileWrite(pb1, st1);
        if (pb2 >= 0) tileWrite(pb2, st2);
        __syncthreads();                  // h_{li+1} visible
    }

    // =================== output projection ===================
    if (tid < TL) {
        const int row = HALO + tid;
        float accp = 0.0f;
        #pragma unroll
        for (int m = 0; m < 16; ++m) {
            const uint4 u = *(const uint4*)(hb + HOFF(row, m * 8));
            const float4 w0v = *(const float4*)(out_w + m * 8);
            const float4 w1v = *(const float4*)(out_w + m * 8 + 4);
            const float2 p0 = unpk(u.x), p1 = unpk(u.y), p2 = unpk(u.z), p3 = unpk(u.w);
            accp = fmaf(w0v.x, p0.x, accp);
            accp = fmaf(w0v.y, p0.y, accp);
            accp = fmaf(w0v.z, p1.x, accp);
            accp = fmaf(w0v.w, p1.y, accp);
            accp = fmaf(w1v.x, p2.x, accp);
            accp = fmaf(w1v.y, p2.y, accp);
            accp = fmaf(w1v.z, p3.x, accp);
            accp = fmaf(w1v.w, p3.y, accp);
        }
        out[(size_t)b * L + s + tid] = accp + out_b[0];
    }
}

extern "C" void kernel_launch(void* const* d_in, const int* in_sizes, int n_in,
                              void* d_out, int out_size, void* d_ws, size_t ws_size,
                              hipStream_t stream) {
    const float* x         = (const float*)d_in[0];
    const float* sc_w      = (const float*)d_in[1];
    const float* pw_w0     = (const float*)d_in[2];
    const float* pw_w_rest = (const float*)d_in[3];
    const float* pw_b      = (const float*)d_in[4];
    const float* bn_g      = (const float*)d_in[5];
    const float* bn_b      = (const float*)d_in[6];
    const float* bn_m      = (const float*)d_in[7];
    const float* bn_v      = (const float*)d_in[8];
    const float* res_w     = (const float*)d_in[9];
    const float* res_b     = (const float*)d_in[10];
    const float* out_w     = (const float*)d_in[11];
    const float* out_b     = (const float*)d_in[12];
    float* out = (float*)d_out;

    unsigned short* Wsh = (unsigned short*)d_ws;               // 128 KiB
    float* prm = (float*)((char*)d_ws + 131072);               // 4 KiB

    prep<<<dim3(128), 512, 0, stream>>>(pw_w0, pw_w_rest, res_w, pw_b,
                                        bn_g, bn_b, bn_m, bn_v, Wsh, prm);
    tcn_mfma<<<dim3(NT, B_), 512, 0, stream>>>(x, sc_w, res_b, out_w, out_b,
                                               Wsh, prm, out);
}

// Round 7
// 86.464 us; speedup vs baseline: 5.8801x; 5.8801x over previous
//
#include <hip/hip_runtime.h>
#include <hip/hip_fp16.h>

namespace {
constexpr int B_   = 32;
constexpr int CIN  = 64;
constexpr int H    = 128;
constexpr int L    = 4096;
constexpr int TL   = 96;            // output positions per block
constexpr int HALO = 30;
constexpr int ROWS = 126;           // HALO + TL
constexpr int NTILES = (L + TL - 1) / TL;  // 43
constexpr float EPS = 1e-5f;
}

typedef __attribute__((ext_vector_type(8))) _Float16 half8;   // 8 f16 (4 VGPRs)
typedef __attribute__((ext_vector_type(4))) float f32x4;

union FragU { unsigned u[4]; half8 h; };

// f16 h tile, position-major [row][128 ch], 256 B/row, 16B-chunk XOR swizzle:
// chunk' = chunk ^ (row & 15) -> 16 consecutive rows hit 16 distinct chunks.
__device__ __forceinline__ int HOFF(int row, int ch) {
    return (row << 8) + ((((ch >> 3) ^ (row & 15)) << 4) | ((ch & 7) << 1));
}
__device__ __forceinline__ float2 unpk(unsigned u) {          // (lo, hi) f16 -> f32
    union { unsigned u; __half2 h; } c; c.u = u;
    return __half22float2(c.h);
}
__device__ __forceinline__ float f16lo(unsigned short u) {
    __half_raw r; r.x = u;
    return __half2float(__half(r));
}
__device__ __forceinline__ unsigned pk(float a, float b) {    // lo=f16(a), hi=f16(b), RN
    union { __half2 h; unsigned u; } c;
    c.h = __floats2half2_rn(a, b);
    return c.u;
}

// ---- prep: weights f32 -> f16 in exact MFMA B-fragment layout; BN folded params ----
// frag element j of lane: n = ot*16 + (lane&15), k = kt*32 + (lane>>4)*4 + (j&3) + 16*(j>>2)
__global__ void prep(const float* __restrict__ pw_w0,
                     const float* __restrict__ pw_w_rest,
                     const float* __restrict__ res_w,
                     const float* __restrict__ pw_b,
                     const float* __restrict__ bn_g,
                     const float* __restrict__ bn_b,
                     const float* __restrict__ bn_m,
                     const float* __restrict__ bn_v,
                     unsigned short* __restrict__ Wsh,   // 65536 f16 (128 KiB)
                     float* __restrict__ prm)            // 1024 f32
{
    const int g = blockIdx.x * 512 + threadIdx.x;        // one f16 each
    {
        const int F = g >> 9;            // frag 0..127
        const int r = g & 511;
        const int lane = r >> 3, j = r & 7;
        const int blk = F >> 5;          // 0:L0(Y+R) 1..3:L1..L3
        const int f = F & 31;
        float v;
        if (blk == 0) {
            const int ff = f & 15;                        // Y: f=0..15, R: f=16..31
            const int kt = ff >> 3, ot = ff & 7;          // K=64 -> kt 0..1
            const int n = ot * 16 + (lane & 15);
            const int k = kt * 32 + ((lane >> 4) << 2) + (j & 3) + ((j >> 2) << 4);
            const float* src = (f >> 4) ? res_w : pw_w0;
            v = src[n * 64 + k];
        } else {
            const int kt = f >> 3, ot = f & 7;            // K=128 -> kt 0..3
            const int n = ot * 16 + (lane & 15);
            const int k = kt * 32 + ((lane >> 4) << 2) + (j & 3) + ((j >> 2) << 4);
            v = pw_w_rest[(size_t)(blk - 1) * H * H + n * H + k];
        }
        const __half hv = __float2half(v);
        Wsh[g] = __half_as_ushort(hv);
    }
    if (blockIdx.x == 0) {
        for (int idx = threadIdx.x; idx < 1024; idx += 512) {
            const int li = idx >> 8;
            const int rest = idx & 255;
            const int ch = rest & 127;
            const int isC = rest >> 7;
            const float A  = bn_g[li * H + ch] * rsqrtf(bn_v[li * H + ch] + EPS);
            const float Cc = fmaf(A, pw_b[li * H + ch] - bn_m[li * H + ch], bn_b[li * H + ch]);
            prm[li * 256 + isC * 128 + ch] = isC ? Cc : A;
        }
    }
}

__global__ __launch_bounds__(512, 2) void tcn_mfma(
    const float* __restrict__ x,
    const float* __restrict__ sc_w,
    const float* __restrict__ res_b,
    const float* __restrict__ out_w,
    const float* __restrict__ out_b,
    const unsigned short* __restrict__ Wsh,
    const float* __restrict__ prm,
    float* __restrict__ out)
{
    __shared__ __align__(16) char smem[128 * 256 + 32768];  // 64 KiB -> 2 blocks/CU
    char* hb = smem;                     // f16 h [128 rows][128 ch] swizzled
    char* Wl = smem + 128 * 256;         // 32 KiB staged B-fragments

    const int tile = blockIdx.x;
    const int b    = blockIdx.y;
    const int s    = tile * TL;
    const int tid  = threadIdx.x;
    const int lane = tid & 63;
    const int wave = tid >> 6;

    // ---- stage x -> f16, transposed+swizzled ----
    const float* xb = x + (size_t)b * CIN * L;
    for (int c = wave; c < CIN; c += 8) {
        for (int j = lane; j < ROWS; j += 64) {
            const int p = s - HALO + j;
            float v = 0.0f;
            if (p >= 0) v = xb[(size_t)c * L + (p < L ? p : L - 1)];  // tail garbage masked at out
            *(unsigned short*)(hb + HOFF(j, c)) = __half_as_ushort(__float2half(v));
        }
    }

    auto stageW = [&](int layerBlk) {     // 32 KiB global -> LDS
        const unsigned short* src = Wsh + layerBlk * 16384;
        #pragma unroll
        for (int it = 0; it < 4; ++it) {
            const int idx = it * 512 + tid;
            *(uint4*)(Wl + idx * 16) = *(const uint4*)(src + idx * 8);
        }
    };
    stageW(0);

    const float w00 = sc_w[0], w01 = sc_w[1], w02 = sc_w[2];

    auto tileWrite = [&](int pb, const unsigned (&stash)[16]) {
        const int o0 = lane & 15;
        const int coff = (lane >> 4) << 2;
        #pragma unroll
        for (int ot = 0; ot < 8; ++ot) {
            const int o = ot * 16 + o0;
            const unsigned wa = stash[ot * 2], wb = stash[ot * 2 + 1];
            *(unsigned short*)(hb + HOFF(pb + coff + 0, o)) = (unsigned short)(wa & 0xffff);
            *(unsigned short*)(hb + HOFF(pb + coff + 1, o)) = (unsigned short)(wa >> 16);
            *(unsigned short*)(hb + HOFF(pb + coff + 2, o)) = (unsigned short)(wb & 0xffff);
            *(unsigned short*)(hb + HOFF(pb + coff + 3, o)) = (unsigned short)(wb >> 16);
        }
    };

    __syncthreads();   // x + W0 staged

    // =================== layer 0: Y-GEMM (K=64) + residual 1x1 GEMM ===================
    {
        const int pb = min(2 + 16 * wave, ROWS - 16);     // one 16-row tile per wave
        unsigned st[16];
        {
            f32x4 accY[8], accR[8];
            #pragma unroll
            for (int ot = 0; ot < 8; ++ot) { accY[ot] = f32x4{0,0,0,0}; accR[ot] = f32x4{0,0,0,0}; }
            const int row0 = pb + (lane & 15);
            const int coff = (lane >> 4) << 2;
            #pragma unroll
            for (int kt = 0; kt < 2; ++kt) {
                const int cb = kt * 32 + coff;
                const uint2 u0a = *(const uint2*)(hb + HOFF(row0,     cb));
                const uint2 u0b = *(const uint2*)(hb + HOFF(row0,     cb + 16));
                const uint2 u1a = *(const uint2*)(hb + HOFF(row0 - 1, cb));
                const uint2 u1b = *(const uint2*)(hb + HOFF(row0 - 1, cb + 16));
                const uint2 u2a = *(const uint2*)(hb + HOFF(row0 - 2, cb));
                const uint2 u2b = *(const uint2*)(hb + HOFF(row0 - 2, cb + 16));
                const unsigned q0[4] = {u0a.x, u0a.y, u0b.x, u0b.y};
                const unsigned q1[4] = {u1a.x, u1a.y, u1b.x, u1b.y};
                const unsigned q2[4] = {u2a.x, u2a.y, u2b.x, u2b.y};
                FragU aU, rU;
                #pragma unroll
                for (int q = 0; q < 4; ++q) {
                    const float2 t0 = unpk(q0[q]);
                    const float2 t1 = unpk(q1[q]);
                    const float2 t2 = unpk(q2[q]);
                    const float dl = fmaf(w02, t0.x, fmaf(w01, t1.x, w00 * t2.x));
                    const float dh = fmaf(w02, t0.y, fmaf(w01, t1.y, w00 * t2.y));
                    aU.u[q] = pk(dl, dh);
                    rU.u[q] = q0[q];                   // raw x taps = residual A-frag
                }
                #pragma unroll
                for (int ot = 0; ot < 8; ++ot) {
                    const half8 bY = *(const half8*)(Wl + (kt * 8 + ot) * 1024 + lane * 16);
                    accY[ot] = __builtin_amdgcn_mfma_f32_16x16x32_f16(aU.h, bY, accY[ot], 0, 0, 0);
                }
                #pragma unroll
                for (int ot = 0; ot < 8; ++ot) {
                    const half8 bR = *(const half8*)(Wl + (16 + kt * 8 + ot) * 1024 + lane * 16);
                    accR[ot] = __builtin_amdgcn_mfma_f32_16x16x32_f16(rU.h, bR, accR[ot], 0, 0, 0);
                }
            }
            #pragma unroll
            for (int ot = 0; ot < 8; ++ot) {
                const int o = ot * 16 + (lane & 15);
                const float A  = prm[o];
                const float Cc = prm[128 + o];
                const float rb = res_b[o];
                float v[4];
                #pragma unroll
                for (int r = 0; r < 4; ++r) {
                    const int row = pb + coff + r;
                    const float y = fmaxf(fmaf(A, accY[ot][r], Cc), 0.0f);
                    float vv = fmaxf(y + accR[ot][r] + rb, 0.0f);
                    if (s - HALO + row < 0) vv = 0.0f;   // causal zero-pad (tile 0)
                    v[r] = vv;
                }
                st[ot * 2]     = pk(v[0], v[1]);
                st[ot * 2 + 1] = pk(v[2], v[3]);
            }
        }
        __syncthreads();                  // all reads of x done
        tileWrite(pb, st);
        __syncthreads();                  // h1 visible
    }

    // =================== layers 1..3 ===================
    #pragma unroll
    for (int li = 1; li < 4; ++li) {
        const int dil = 1 << li;
        const int jstart = (li == 1) ? 6 : (li == 2) ? 14 : 30;
        const float lw0 = sc_w[li * 3], lw1 = sc_w[li * 3 + 1], lw2 = sc_w[li * 3 + 2];

        stageW(li);                       // Wl reads of prev layer finished pre-barrier
        __syncthreads();

        const int pb = min(jstart + 16 * wave, ROWS - 16);  // one tile per wave
        unsigned st[16];
        {
            f32x4 acc[8];
            #pragma unroll
            for (int ot = 0; ot < 8; ++ot) acc[ot] = f32x4{0,0,0,0};
            const int row0 = pb + (lane & 15);
            const int coff = (lane >> 4) << 2;
            #pragma unroll
            for (int kt = 0; kt < 4; ++kt) {
                const int cb = kt * 32 + coff;
                const uint2 u0a = *(const uint2*)(hb + HOFF(row0,           cb));
                const uint2 u0b = *(const uint2*)(hb + HOFF(row0,           cb + 16));
                const uint2 u1a = *(const uint2*)(hb + HOFF(row0 - dil,     cb));
                const uint2 u1b = *(const uint2*)(hb + HOFF(row0 - dil,     cb + 16));
                const uint2 u2a = *(const uint2*)(hb + HOFF(row0 - 2 * dil, cb));
                const uint2 u2b = *(const uint2*)(hb + HOFF(row0 - 2 * dil, cb + 16));
                const unsigned q0[4] = {u0a.x, u0a.y, u0b.x, u0b.y};
                const unsigned q1[4] = {u1a.x, u1a.y, u1b.x, u1b.y};
                const unsigned q2[4] = {u2a.x, u2a.y, u2b.x, u2b.y};
                FragU aU;
                #pragma unroll
                for (int q = 0; q < 4; ++q) {
                    const float2 t0 = unpk(q0[q]);
                    const float2 t1 = unpk(q1[q]);
                    const float2 t2 = unpk(q2[q]);
                    const float dl = fmaf(lw2, t0.x, fmaf(lw1, t1.x, lw0 * t2.x));
                    const float dh = fmaf(lw2, t0.y, fmaf(lw1, t1.y, lw0 * t2.y));
                    aU.u[q] = pk(dl, dh);
                }
                #pragma unroll
                for (int ot = 0; ot < 8; ++ot) {
                    const half8 bb = *(const half8*)(Wl + (kt * 8 + ot) * 1024 + lane * 16);
                    acc[ot] = __builtin_amdgcn_mfma_f32_16x16x32_f16(aU.h, bb, acc[ot], 0, 0, 0);
                }
            }
            #pragma unroll
            for (int ot = 0; ot < 8; ++ot) {
                const int o = ot * 16 + (lane & 15);
                const float A  = prm[li * 256 + o];
                const float Cc = prm[li * 256 + 128 + o];
                float v[4];
                #pragma unroll
                for (int r = 0; r < 4; ++r) {
                    const int row = pb + coff + r;
                    const float y = fmaxf(fmaf(A, acc[ot][r], Cc), 0.0f);
                    const unsigned short rr = *(const unsigned short*)(hb + HOFF(row, o));
                    float vv = fmaxf(y + f16lo(rr), 0.0f);        // identity residual
                    if (s - HALO + row < 0) vv = 0.0f;            // causal zero-pad (tile 0)
                    v[r] = vv;
                }
                st[ot * 2]     = pk(v[0], v[1]);
                st[ot * 2 + 1] = pk(v[2], v[3]);
            }
        }
        __syncthreads();                  // all reads of h_li done
        tileWrite(pb, st);
        __syncthreads();                  // h_{li+1} visible
    }

    // =================== output projection ===================
    if (tid < TL) {
        const int p = s + tid;
        if (p < L) {
            const int row = HALO + tid;
            float accp = 0.0f;
            #pragma unroll
            for (int m = 0; m < 16; ++m) {
                const uint4 u = *(const uint4*)(hb + HOFF(row, m * 8));
                const float4 w0v = *(const float4*)(out_w + m * 8);
                const float4 w1v = *(const float4*)(out_w + m * 8 + 4);
                const float2 p0 = unpk(u.x), p1 = unpk(u.y), p2 = unpk(u.z), p3 = unpk(u.w);
                accp = fmaf(w0v.x, p0.x, accp);
                accp = fmaf(w0v.y, p0.y, accp);
                accp = fmaf(w0v.z, p1.x, accp);
                accp = fmaf(w0v.w, p1.y, accp);
                accp = fmaf(w1v.x, p2.x, accp);
                accp = fmaf(w1v.y, p2.y, accp);
                accp = fmaf(w1v.z, p3.x, accp);
                accp = fmaf(w1v.w, p3.y, accp);
            }
            out[(size_t)b * L + p] = accp + out_b[0];
        }
    }
}

extern "C" void kernel_launch(void* const* d_in, const int* in_sizes, int n_in,
                              void* d_out, int out_size, void* d_ws, size_t ws_size,
                              hipStream_t stream) {
    const float* x         = (const float*)d_in[0];
    const float* sc_w      = (const float*)d_in[1];
    const float* pw_w0     = (const float*)d_in[2];
    const float* pw_w_rest = (const float*)d_in[3];
    const float* pw_b      = (const float*)d_in[4];
    const float* bn_g      = (const float*)d_in[5];
    const float* bn_b      = (const float*)d_in[6];
    const float* bn_m      = (const float*)d_in[7];
    const float* bn_v      = (const float*)d_in[8];
    const float* res_w     = (const float*)d_in[9];
    const float* res_b     = (const float*)d_in[10];
    const float* out_w     = (const float*)d_in[11];
    const float* out_b     = (const float*)d_in[12];
    float* out = (float*)d_out;

    unsigned short* Wsh = (unsigned short*)d_ws;               // 128 KiB
    float* prm = (float*)((char*)d_ws + 131072);               // 4 KiB

    prep<<<dim3(128), 512, 0, stream>>>(pw_w0, pw_w_rest, res_w, pw_b,
                                        bn_g, bn_b, bn_m, bn_v, Wsh, prm);
    tcn_mfma<<<dim3(NTILES, B_), 512, 0, stream>>>(x, sc_w, res_b, out_w, out_b,
                                                   Wsh, prm, out);
}